// Round 5
// baseline (525.394 us; speedup 1.0000x reference)
//
#include <hip/hip_runtime.h>
#include <cstdint>
#include <cstddef>

typedef __bf16 bf16_t;
typedef __bf16 bf16x8 __attribute__((ext_vector_type(8)));
typedef float  f32x4  __attribute__((ext_vector_type(4)));

#define HEADS    8
#define DIM_HEAD 64
#define SLICE    32
#define DIMC     512      // DIM == INNER == 512
#define BATCH    8
#define NSEQ     8192
#define NTOK     65536

// Async global->LDS, 16B per lane. LDS dest is wave-uniform base + lane*16.
__device__ __forceinline__ void gl2lds16(const bf16_t* g, bf16_t* l) {
  __builtin_amdgcn_global_load_lds(
      (const __attribute__((address_space(1))) uint32_t*)g,
      (__attribute__((address_space(3))) uint32_t*)l, 16, 0, 0);
}

// ---------------------------------------------------------------------------
// Weight prep: WcT[col][cin] (bf16), per-head column order:
//   col = h*128 + r;  r<32 -> Wq[:,r], r<64 -> Wk[:,r-32], else Wv[:,r-64]
// ---------------------------------------------------------------------------
__global__ __launch_bounds__(256) void wprep_kernel(
    const float* __restrict__ W_in, const float* __restrict__ b_in,
    const float* __restrict__ Wq,   const float* __restrict__ Wk,
    const float* __restrict__ Wv,
    bf16_t* __restrict__ WcT, float* __restrict__ bias_c) {
  __shared__ float sW[8192];                 // Wq[0..2048) Wk[2048..4096) Wv[4096..8192)
  for (int t = threadIdx.x; t < 2048; t += 256) { sW[t] = Wq[t]; sW[2048 + t] = Wk[t]; }
  for (int t = threadIdx.x; t < 4096; t += 256) sW[4096 + t] = Wv[t];
  __syncthreads();

  const int T  = blockIdx.x * 256 + threadIdx.x;
  const int NT = gridDim.x * 256;
  for (int idx = T; idx < 1024 * DIMC; idx += NT) {
    const int col = idx >> 9, cin = idx & 511;
    const int h = col >> 7, r = col & 127;
    int base, ldw, j;
    if (r < 32)      { j = r;      base = 0;    ldw = 32; }
    else if (r < 64) { j = r - 32; base = 2048; ldw = 32; }
    else             { j = r - 64; base = 4096; ldw = 64; }
    const float4* vp = reinterpret_cast<const float4*>(W_in + (size_t)cin * DIMC + h * DIM_HEAD);
    float acc = 0.f;
    #pragma unroll
    for (int d4 = 0; d4 < 16; ++d4) {
      const float4 v = vp[d4];
      acc += v.x * sW[base + (4*d4+0)*ldw + j];
      acc += v.y * sW[base + (4*d4+1)*ldw + j];
      acc += v.z * sW[base + (4*d4+2)*ldw + j];
      acc += v.w * sW[base + (4*d4+3)*ldw + j];
    }
    WcT[(size_t)col * DIMC + cin] = (bf16_t)acc;
  }
  if (T < 1024) {
    const int col = T;
    const int h = col >> 7, r = col & 127;
    int base, ldw, j;
    if (r < 32)      { j = r;      base = 0;    ldw = 32; }
    else if (r < 64) { j = r - 32; base = 2048; ldw = 32; }
    else             { j = r - 64; base = 4096; ldw = 64; }
    const float* vec = b_in + h * DIM_HEAD;
    float acc = 0.f;
    #pragma unroll 8
    for (int d = 0; d < DIM_HEAD; ++d) acc += vec[d] * sW[base + d * ldw + j];
    bias_c[col] = acc;
  }
}

// ---------------------------------------------------------------------------
// GEMM1: 128x128xBK64 (m97 structure, 4 waves, XOR-swizzled unpadded LDS).
// A = x in FP32 read directly (xcast fused away): reg-staged 8xfloat4/thread,
// cvt->bf16, 4x ds_write_b128 into the swizzled layout; next tile's f32 chunk
// is register-prefetched under a counted vmcnt(8). Issue order B-staging ->
// xr-prefetch is PINNED by sched_barrier(0) so vmcnt(8) provably covers B.
// B = WcT bf16 via global_load_lds.
// Fused epilogue (per-head n-block): q->softmax->bf16 q' [NTOK,256];
// k->exp->LDS + den partial; v->LDS; kv[32x64] = ek^T @ v via MFMA;
// per-block f32 partials (64 per (b,h)), reduced by kvreduce.
// ---------------------------------------------------------------------------
__global__ __launch_bounds__(256) void gemm1_kernel(
    const float* __restrict__ X, const bf16_t* __restrict__ Bt,
    bf16_t* __restrict__ qprime, const float* __restrict__ bias,
    float* __restrict__ kvp_g, float* __restrict__ denp_g)
{
  __shared__ bf16_t As[128 * 64];   // unpadded; swizzled-chunk layout
  __shared__ bf16_t Bs[128 * 64];
  const int tid = threadIdx.x;
  const int p = blockIdx.y * gridDim.x + blockIdx.x;
  const int mblk = (p & 7) + ((p >> 6) << 3);
  const int nblk = (p >> 3) & 7;            // head
  const int m0 = mblk * 128, n0 = nblk * 128;
  const int wave = tid >> 6, lane = tid & 63;
  const int cg = lane & 15, qd = lane >> 4;
  const int wm = (wave & 1) * 64, wn = (wave >> 1) * 64;
  const int srw = lane >> 3;
  const int gchunk = (lane & 7) ^ srw;      // XOR column-chunk swizzle (B staging)
  const int chb = cg & 7;

  // A reg-staging mapping: 2 threads per row, 32 f32 each
  const int arow = tid >> 1;                // 0..127
  const int akh  = (tid & 1) * 32;          // k-offset 0 / 32
  const float* xrow = X + (size_t)(m0 + arow) * DIMC + akh;

  f32x4 acc[4][4];
  #pragma unroll
  for (int i = 0; i < 4; ++i)
    #pragma unroll
    for (int j = 0; j < 4; ++j) acc[i][j] = (f32x4){0.f, 0.f, 0.f, 0.f};

  float4 xr[8];
  #pragma unroll
  for (int l = 0; l < 8; ++l) xr[l] = *reinterpret_cast<const float4*>(xrow + l * 4);

  for (int k0 = 0; k0 < DIMC; k0 += 64) {
    __syncthreads();   // prev tile's readers done
    // ---- A: cvt f32->bf16, swizzled ds_write (4 x 16B) ----
    #pragma unroll
    for (int c = 0; c < 4; ++c) {
      const float4 u = xr[2 * c], v = xr[2 * c + 1];
      bf16x8 w;
      w[0] = (bf16_t)u.x; w[1] = (bf16_t)u.y; w[2] = (bf16_t)u.z; w[3] = (bf16_t)u.w;
      w[4] = (bf16_t)v.x; w[5] = (bf16_t)v.y; w[6] = (bf16_t)v.z; w[7] = (bf16_t)v.w;
      const int g = (akh >> 3) + c;
      *reinterpret_cast<bf16x8*>(As + arow * 64 + ((g ^ (arow & 7)) << 3)) = w;
    }
    // ---- B: async staging (must be issued BEFORE xr prefetch) ----
    #pragma unroll
    for (int i = 0; i < 4; ++i) {
      const int c = wave * 4 + i;
      const int row = c * 8 + srw;
      gl2lds16(Bt + (size_t)(n0 + row) * DIMC + k0 + gchunk * 8, Bs + c * 512 + lane * 8);
    }
    __builtin_amdgcn_sched_barrier(0);   // pin VMEM issue order: B before xr
    // ---- register-prefetch next A chunk; counted wait keeps it in flight ----
    if (k0 + 64 < DIMC) {
      #pragma unroll
      for (int l = 0; l < 8; ++l)
        xr[l] = *reinterpret_cast<const float4*>(xrow + k0 + 64 + l * 4);
      asm volatile("s_waitcnt vmcnt(8)" ::: "memory");   // B landed; xr in flight
    } else {
      asm volatile("s_waitcnt vmcnt(0)" ::: "memory");
    }
    asm volatile("s_waitcnt lgkmcnt(0)" ::: "memory");   // own A ds_writes landed
    __builtin_amdgcn_sched_barrier(0);
    __builtin_amdgcn_s_barrier();
    // ---- compute ----
    #pragma unroll
    for (int ks = 0; ks < 64; ks += 32) {
      const int k4 = ks >> 3;
      bf16x8 af[4], bfr[4];
      #pragma unroll
      for (int i = 0; i < 4; ++i) {
        const int ch = (qd + k4) ^ chb;
        af[i] = *reinterpret_cast<const bf16x8*>(As + (wm + 16 * i + cg) * 64 + ch * 8);
      }
      #pragma unroll
      for (int j = 0; j < 4; ++j) {
        const int ch = (qd + k4) ^ chb;
        bfr[j] = *reinterpret_cast<const bf16x8*>(Bs + (wn + 16 * j + cg) * 64 + ch * 8);
      }
      #pragma unroll
      for (int i = 0; i < 4; ++i)
        #pragma unroll
        for (int j = 0; j < 4; ++j)
          acc[i][j] = __builtin_amdgcn_mfma_f32_16x16x32_bf16(af[i], bfr[j], acc[i][j], 0, 0, 0);
    }
  }

  // ---- fused epilogue (round-1 verified) ----
  const int h   = nblk;
  const int bat = mblk >> 6;        // 64 m-blocks per batch
  const int mb  = mblk & 63;
  const int bh  = bat * HEADS + h;
  __syncthreads();                   // all mainloop LDS reads done before reuse
  bf16_t* ekT   = As;                          // [32][128] bf16, XOR-swizzled, 8KB
  bf16_t* vT    = Bs;                          // [64][128] bf16, XOR-swizzled, 16KB
  float*  den_s = (float*)(void*)(As + 4096);  // bytes 8192..8447: [2][32] f32

  if (wave < 2) {
    // ---- q softmax over the head's 32 q cols (j=0,1); rows wm..wm+63 ----
    {
      const float b0 = bias[n0 + cg];
      const float b1 = bias[n0 + 16 + cg];
      #pragma unroll
      for (int i = 0; i < 4; ++i) {
        #pragma unroll
        for (int rr = 0; rr < 4; ++rr) {
          float v0 = acc[i][0][rr] + b0;
          float v1 = acc[i][1][rr] + b1;
          float mx = fmaxf(v0, v1);
          #pragma unroll
          for (int d = 1; d < 16; d <<= 1) mx = fmaxf(mx, __shfl_xor(mx, d, 64));
          const float e0 = __expf(v0 - mx), e1 = __expf(v1 - mx);
          float s = e0 + e1;
          #pragma unroll
          for (int d = 1; d < 16; d <<= 1) s += __shfl_xor(s, d, 64);
          const float rs = 1.f / s;
          const int row = m0 + wm + 16 * i + qd * 4 + rr;
          bf16_t* crow = qprime + (size_t)row * 256 + h * SLICE;
          crow[cg]      = (bf16_t)(e0 * rs);
          crow[16 + cg] = (bf16_t)(e1 * rs);
        }
      }
    }
    // ---- ek = exp(k + bias) (j=2,3) -> swizzled LDS + den partial ----
    #pragma unroll
    for (int j = 2; j < 4; ++j) {
      const int s_i = 16 * (j - 2) + cg;
      const float bk = bias[n0 + 16 * j + cg];
      float dsum = 0.f;
      #pragma unroll
      for (int i = 0; i < 4; ++i) {
        #pragma unroll
        for (int rr = 0; rr < 4; ++rr) {
          const float e = __expf(acc[i][j][rr] + bk);
          dsum += e;
          const int n = wm + 16 * i + qd * 4 + rr;
          *(bf16_t*)((char*)ekT + (((s_i << 8) + 2 * n) ^ ((s_i & 7) << 4))) = (bf16_t)e;
        }
      }
      dsum += __shfl_xor(dsum, 16, 64);   // reduce across qd group
      dsum += __shfl_xor(dsum, 32, 64);
      if (qd == 0) den_s[wave * 32 + s_i] = dsum;
    }
  } else {
    // ---- v + bias -> swizzled LDS (64 cols); rows wm..wm+63 ----
    #pragma unroll
    for (int j = 0; j < 4; ++j) {
      const int c = 16 * j + cg;
      const float bv = bias[n0 + 64 + c];
      #pragma unroll
      for (int i = 0; i < 4; ++i) {
        #pragma unroll
        for (int rr = 0; rr < 4; ++rr) {
          const float vv = acc[i][j][rr] + bv;
          const int n = wm + 16 * i + qd * 4 + rr;
          *(bf16_t*)((char*)vT + (((c << 8) + 2 * n) ^ ((c & 7) << 4))) = (bf16_t)vv;
        }
      }
    }
  }
  __syncthreads();
  if (tid < SLICE)
    denp_g[((size_t)bh * 64 + mb) * SLICE + tid] = den_s[tid] + den_s[32 + tid];

  // ---- kv outer product: kv[s][c] = sum_{n<128} ek[n,s] * v[n,c] ----
  const int st = wave & 1;
  const int sA = st * 16 + cg;
  float* kvp = kvp_g + ((size_t)bh * 64 + mb) * (SLICE * DIM_HEAD);
  #pragma unroll
  for (int ci = 0; ci < 2; ++ci) {
    const int ct = (wave >> 1) * 2 + ci;
    const int cB = ct * 16 + cg;
    f32x4 kacc = (f32x4){0.f, 0.f, 0.f, 0.f};
    #pragma unroll
    for (int ks = 0; ks < 4; ++ks) {
      bf16x8 afr = *(const bf16x8*)((const char*)ekT +
                     (((sA << 8) + ks * 64 + qd * 16) ^ ((sA & 7) << 4)));
      bf16x8 bfr2 = *(const bf16x8*)((const char*)vT +
                     (((cB << 8) + ks * 64 + qd * 16) ^ ((cB & 7) << 4)));
      kacc = __builtin_amdgcn_mfma_f32_16x16x32_bf16(afr, bfr2, kacc, 0, 0, 0);
    }
    #pragma unroll
    for (int r = 0; r < 4; ++r)
      kvp[(st * 16 + qd * 4 + r) * DIM_HEAD + cB] = kacc[r];
  }
}

// ---------------------------------------------------------------------------
// GEMM3: 128x128xBK64, round-1 structure verbatim (gl2lds both sides,
// __syncthreads both sides), dense q' (lda=256), fp32 out + bias, batched.
// ---------------------------------------------------------------------------
__global__ __launch_bounds__(256) void gemm3_kernel(
    const bf16_t* __restrict__ A, const bf16_t* __restrict__ Bt,
    float* __restrict__ out, const float* __restrict__ bias)
{
  __shared__ bf16_t As[128 * 64];
  __shared__ bf16_t Bs[128 * 64];
  const int tid = threadIdx.x;
  const int p = blockIdx.y * gridDim.x + blockIdx.x;
  const int mblk = (p & 7) + ((p >> 5) << 3);
  const int nblk = (p >> 3) & 3;
  const int m0 = mblk * 128, n0 = nblk * 128;
  const int bz = blockIdx.z;
  const int wave = tid >> 6, lane = tid & 63;
  const int cg = lane & 15, qd = lane >> 4;
  const int wm = (wave & 1) * 64, wn = (wave >> 1) * 64;
  const int srw = lane >> 3;
  const int gchunk = (lane & 7) ^ srw;
  const int chb = cg & 7;

  const bf16_t* Ab = A + (size_t)bz * NSEQ * 256;
  const bf16_t* Bb = Bt + (size_t)bz * DIMC * 256;

  f32x4 acc[4][4];
  #pragma unroll
  for (int i = 0; i < 4; ++i)
    #pragma unroll
    for (int j = 0; j < 4; ++j) acc[i][j] = (f32x4){0.f, 0.f, 0.f, 0.f};

  for (int k0 = 0; k0 < 256; k0 += 64) {
    __syncthreads();
    #pragma unroll
    for (int i = 0; i < 4; ++i) {
      const int c = wave * 4 + i;
      const int row = c * 8 + srw;
      gl2lds16(Ab + (size_t)(m0 + row) * 256 + k0 + gchunk * 8, As + c * 512 + lane * 8);
    }
    #pragma unroll
    for (int i = 0; i < 4; ++i) {
      const int c = wave * 4 + i;
      const int row = c * 8 + srw;
      gl2lds16(Bb + (size_t)(n0 + row) * 256 + k0 + gchunk * 8, Bs + c * 512 + lane * 8);
    }
    __syncthreads();
    #pragma unroll
    for (int ks = 0; ks < 64; ks += 32) {
      const int k4 = ks >> 3;
      bf16x8 af[4], bfr[4];
      #pragma unroll
      for (int i = 0; i < 4; ++i) {
        const int ch = (qd + k4) ^ chb;
        af[i] = *reinterpret_cast<const bf16x8*>(As + (wm + 16 * i + cg) * 64 + ch * 8);
      }
      #pragma unroll
      for (int j = 0; j < 4; ++j) {
        const int ch = (qd + k4) ^ chb;
        bfr[j] = *reinterpret_cast<const bf16x8*>(Bs + (wn + 16 * j + cg) * 64 + ch * 8);
      }
      #pragma unroll
      for (int i = 0; i < 4; ++i)
        #pragma unroll
        for (int j = 0; j < 4; ++j)
          acc[i][j] = __builtin_amdgcn_mfma_f32_16x16x32_bf16(af[i], bfr[j], acc[i][j], 0, 0, 0);
    }
  }

  float* ob = out + (size_t)bz * NSEQ * DIMC;
  #pragma unroll
  for (int j = 0; j < 4; ++j) {
    const int col = n0 + wn + 16 * j + cg;
    const float bv = bias[col];
    #pragma unroll
    for (int i = 0; i < 4; ++i) {
      #pragma unroll
      for (int rr = 0; rr < 4; ++rr) {
        const int row = m0 + wm + 16 * i + qd * 4 + rr;
        ob[(size_t)row * DIMC + col] = acc[i][j][rr] + bv;
      }
    }
  }
}

// ---------------------------------------------------------------------------
// kv partial reduction: kv_red[bh][2048] = sum_mb kv_part[bh][mb][2048]
// ---------------------------------------------------------------------------
__global__ __launch_bounds__(256) void kvreduce_kernel(const float* __restrict__ kv_part,
                                                       const float* __restrict__ den_part,
                                                       float* __restrict__ kv_red,
                                                       float* __restrict__ den_red) {
  const int ch = blockIdx.x, bh = blockIdx.y;
  const int tid = threadIdx.x;
  const float* src = kv_part + (size_t)bh * 64 * 2048 + ch * 256 + tid;
  float s = 0.f;
  #pragma unroll 8
  for (int mb = 0; mb < 64; ++mb) s += src[(size_t)mb * 2048];
  kv_red[(size_t)bh * 2048 + ch * 256 + tid] = s;
  if (ch == 0 && tid < 32) {
    const float* dsrc = den_part + (size_t)bh * 64 * 32 + tid;
    float d = 0.f;
    #pragma unroll 8
    for (int mb = 0; mb < 64; ++mb) d += dsrc[mb * 32];
    den_red[bh * 32 + tid] = d;
  }
}

// ---------------------------------------------------------------------------
// M prep: normalize kv, then Mt[b][outc][h*32+s] = sum_c kvn[s][c]*W_out[h*64+c][outc]
// grid (64 bh, 2 outc-halves), 256 threads (one outc each).
// ---------------------------------------------------------------------------
__global__ __launch_bounds__(256) void mprep_kernel(const float* __restrict__ kv_red,
                                                    const float* __restrict__ den_red,
                                                    const float* __restrict__ W_out,
                                                    bf16_t* __restrict__ Mt) {
  const int bh = blockIdx.x, half = blockIdx.y;
  const int bat = bh >> 3, h = bh & 7;
  const int tid = threadIdx.x;
  __shared__ float kvn[SLICE][DIM_HEAD];   // 8 KB (normalized kv)
  __shared__ float wbuf[8][256];           // 8 KB
  const float* src = kv_red + (size_t)bh * 2048;
  const float* dp  = den_red + bh * 32;
  for (int t = tid; t < 2048; t += 256) kvn[t >> 6][t & 63] = src[t] / dp[t >> 6];

  float accs[SLICE];
  #pragma unroll
  for (int s = 0; s < SLICE; ++s) accs[s] = 0.f;
  for (int cb = 0; cb < DIM_HEAD; cb += 8) {
    __syncthreads();
    for (int t = tid; t < 8 * 256; t += 256)
      wbuf[t >> 8][t & 255] = W_out[(size_t)(h * DIM_HEAD + cb + (t >> 8)) * DIMC + half * 256 + (t & 255)];
    __syncthreads();
    #pragma unroll
    for (int cc = 0; cc < 8; ++cc) {
      const float wv = wbuf[cc][tid];
      #pragma unroll
      for (int s = 0; s < SLICE; ++s) accs[s] += kvn[s][cb + cc] * wv;
    }
  }
  bf16_t* dst = Mt + (size_t)bat * (DIMC * 256) + (size_t)(half * 256 + tid) * 256 + h * SLICE;
  #pragma unroll
  for (int s = 0; s < SLICE; ++s) dst[s] = (bf16_t)accs[s];
}

// ---------------------------------------------------------------------------
extern "C" void kernel_launch(void* const* d_in, const int* in_sizes, int n_in,
                              void* d_out, int out_size, void* d_ws, size_t ws_size,
                              hipStream_t stream) {
  const float* x     = (const float*)d_in[0];
  const float* W_in  = (const float*)d_in[1];
  const float* b_in  = (const float*)d_in[2];
  const float* Wq    = (const float*)d_in[3];
  const float* Wk    = (const float*)d_in[4];
  const float* Wv    = (const float*)d_in[5];
  const float* W_out = (const float*)d_in[6];
  const float* b_out = (const float*)d_in[7];

  uint8_t* ws = (uint8_t*)d_ws;
  bf16_t* qprime   = (bf16_t*)(ws);                     // 65536*256 bf16 = 33554432 B
  bf16_t* WcT      = (bf16_t*)(ws + 33554432ull);       // 1024*512 bf16  = 1048576 B
  float*  bias_c   = (float*) (ws + 34603008ull);       // 1024 f32       = 4096 B
  float*  kv_part  = (float*) (ws + 34607104ull);       // 64*64*2048 f32 = 33554432 B
  float*  den_part = (float*) (ws + 68161536ull);       // 64*64*32 f32   = 524288 B
  float*  kv_red   = (float*) (ws + 68685824ull);       // 64*2048 f32    = 524288 B
  float*  den_red  = (float*) (ws + 69210112ull);       // 64*32 f32      = 8192 B
  bf16_t* Mt       = (bf16_t*)(ws + 69218304ull);       // 8*512*256 bf16 = 2097152 B

  wprep_kernel<<<dim3(256), dim3(256), 0, stream>>>(W_in, b_in, Wq, Wk, Wv, WcT, bias_c);

  // GEMM1: x f32 [65536,512] @ WcT -> q' [65536,256] bf16 + kv/den partials
  gemm1_kernel<<<dim3(8, 512), dim3(256), 0, stream>>>(
      x, WcT, qprime, bias_c, kv_part, den_part);

  kvreduce_kernel<<<dim3(8, 64), dim3(256), 0, stream>>>(kv_part, den_part, kv_red, den_red);
  mprep_kernel<<<dim3(64, 2), dim3(256), 0, stream>>>(kv_red, den_red, W_out, Mt);

  // GEMM3 (batched over b): q' [8192,256] bf16 @ Mt[b] -> out [8192,512] f32
  gemm3_kernel<<<dim3(4, 64, BATCH), dim3(256), 0, stream>>>(
      qprime, Mt, (float*)d_out, b_out);
}